// Round 12
// baseline (168.275 us; speedup 1.0000x reference)
//
#include <hip/hip_runtime.h>

typedef float  f32x4   __attribute__((ext_vector_type(4)));
typedef short  short8  __attribute__((ext_vector_type(8)));
typedef unsigned short ushort8 __attribute__((ext_vector_type(8)));

constexpr int kB = 8;
constexpr int kS = 512;
constexpr int kH = 768;
constexpr int kJM = 384;   // max rows of Eqc / k-extent of attn-bf16 (start in [128,384))

constexpr float kTanhScale = 2.8853900817779268f;  // 2*log2(e)

__device__ __forceinline__ float native_exp2(float x) {
    float r; asm("v_exp_f32 %0, %1" : "=v"(r) : "v"(x)); return r;
}

__device__ __forceinline__ unsigned short bf16_rtn(float x) {
    unsigned u = __float_as_uint(x);
    unsigned r = u + 0x7FFFu + ((u >> 16) & 1u);   // round-to-nearest-even
    return (unsigned short)(r >> 16);
}

__device__ __forceinline__ float waveMax(float v) {
#pragma unroll
    for (int off = 32; off > 0; off >>= 1) v = fmaxf(v, __shfl_xor(v, off, 64));
    return v;
}
__device__ __forceinline__ float waveSum(float v) {
#pragma unroll
    for (int off = 32; off > 0; off >>= 1) v += __shfl_xor(v, off, 64);
    return v;
}

// ---------------- K0: X -> RTN bf16 hi + RTN lo residual; Wa/Ua -> RTN bf16 (hi only).
__global__ __launch_bounds__(256) void k0_convert(
    const float* __restrict__ X, const float* __restrict__ Wa, const float* __restrict__ Ua,
    unsigned short* __restrict__ Xhi, unsigned short* __restrict__ Xlo,
    unsigned short* __restrict__ Wahi, unsigned short* __restrict__ Uahi)
{
    const int i4 = blockIdx.x * 256 + threadIdx.x;
    if (i4 < 786432) {
        float4 v = *(const float4*)(X + (size_t)i4 * 4);
        unsigned short h[4], l[4];
#pragma unroll
        for (int c = 0; c < 4; ++c) {
            float x = (&v.x)[c];
            h[c] = bf16_rtn(x);
            float hf = __uint_as_float((unsigned)h[c] << 16);
            l[c] = bf16_rtn(x - hf);
        }
        *(ushort4*)(Xhi + (size_t)i4 * 4) = make_ushort4(h[0], h[1], h[2], h[3]);
        *(ushort4*)(Xlo + (size_t)i4 * 4) = make_ushort4(l[0], l[1], l[2], l[3]);
    } else {
        const float* src; unsigned short* hi; int off;
        if (i4 < 933888) { src = Wa; hi = Wahi; off = i4 - 786432; }
        else             { src = Ua; hi = Uahi; off = i4 - 933888; }
        float4 v = *(const float4*)(src + (size_t)off * 4);
        *(ushort4*)(hi + (size_t)off * 4) =
            make_ushort4(bf16_rtn(v.x), bf16_rtn(v.y), bf16_rtn(v.z), bf16_rtn(v.w));
    }
}

// ---------------- K1 (MFMA): z=0: Eqc[b][jj][n] = exp2((X·Wa^T+b)*s), jj = t-start
//                             z=1: Ek2[b][kt][n][s&63] = exp2((X·Ua^T+b)*s), cols s < start
// BM=128, BN=96, BK=32; 2-product bf16: (Xhi + Xlo) x W_rtn.
__global__ __launch_bounds__(256) void k1_mfma(
    const unsigned short* __restrict__ Xhi, const unsigned short* __restrict__ Xlo,
    const unsigned short* __restrict__ W0hi, const unsigned short* __restrict__ W1hi,
    const float* __restrict__ b0, const float* __restrict__ b1,
    const int* __restrict__ mask,
    float* __restrict__ Eqc, float* __restrict__ Ek2)
{
    __shared__ char smem[49664];
    unsigned short* Ahi = (unsigned short*)smem;
    unsigned short* Alo = (unsigned short*)(smem + 10240);
    unsigned short* Bhi = (unsigned short*)(smem + 20480);

    const int z = blockIdx.z;
    const unsigned short* Whi = z ? W1hi : W0hi;
    const float* bias = z ? b1 : b0;

    const int m0 = blockIdx.y * 128;
    const int n0 = blockIdx.x * 96;
    const int t  = threadIdx.x;
    const int bI = m0 >> 9;
    const int lb = m0 & (kS - 1);
    const int start = mask[2 * bI];

    if (z == 0) { if (lb + 128 <= start) return; }
    else        { if (lb >= start) return; }

    const int ar = t >> 1, ko = (t & 1) << 4;
    const bool doB = (ar < 96);
    const size_t aoff = (size_t)(m0 + ar) * kH + ko;
    const size_t woff = (size_t)(n0 + ar) * kH + ko;

    const int wid = t >> 6, lane = t & 63;
    const int wr = wid >> 1, wc = wid & 1;
    const int lr = lane & 15, lk = (lane >> 4) << 3;

    f32x4 acc[4][3];
#pragma unroll
    for (int mi = 0; mi < 4; ++mi)
#pragma unroll
        for (int ni = 0; ni < 3; ++ni)
#pragma unroll
            for (int r = 0; r < 4; ++r) acc[mi][ni][r] = 0.0f;

    for (int h0 = 0; h0 < kH; h0 += 32) {
        ushort8 ah0 = *(const ushort8*)(Xhi + aoff + h0);
        ushort8 ah1 = *(const ushort8*)(Xhi + aoff + h0 + 8);
        ushort8 al0 = *(const ushort8*)(Xlo + aoff + h0);
        ushort8 al1 = *(const ushort8*)(Xlo + aoff + h0 + 8);
        ushort8 bh0, bh1;
        if (doB) {
            bh0 = *(const ushort8*)(Whi + woff + h0);
            bh1 = *(const ushort8*)(Whi + woff + h0 + 8);
        }
        __syncthreads();
        *(ushort8*)(Ahi + ar * 40 + ko)     = ah0;
        *(ushort8*)(Ahi + ar * 40 + ko + 8) = ah1;
        *(ushort8*)(Alo + ar * 40 + ko)     = al0;
        *(ushort8*)(Alo + ar * 40 + ko + 8) = al1;
        if (doB) {
            *(ushort8*)(Bhi + ar * 40 + ko)     = bh0;
            *(ushort8*)(Bhi + ar * 40 + ko + 8) = bh1;
        }
        __syncthreads();

        short8 ah[4], al_[4], bh[3];
#pragma unroll
        for (int mi = 0; mi < 4; ++mi) {
            const int row = wr * 64 + mi * 16 + lr;
            ah[mi]  = *(const short8*)(Ahi + row * 40 + lk);
            al_[mi] = *(const short8*)(Alo + row * 40 + lk);
        }
#pragma unroll
        for (int ni = 0; ni < 3; ++ni) {
            const int row = wc * 48 + ni * 16 + lr;
            bh[ni] = *(const short8*)(Bhi + row * 40 + lk);
        }
#pragma unroll
        for (int mi = 0; mi < 4; ++mi)
#pragma unroll
            for (int ni = 0; ni < 3; ++ni)
                acc[mi][ni] = __builtin_amdgcn_mfma_f32_16x16x32_bf16(ah[mi], bh[ni], acc[mi][ni], 0, 0, 0);
#pragma unroll
        for (int mi = 0; mi < 4; ++mi)
#pragma unroll
            for (int ni = 0; ni < 3; ++ni)
                acc[mi][ni] = __builtin_amdgcn_mfma_f32_16x16x32_bf16(al_[mi], bh[ni], acc[mi][ni], 0, 0, 0);
    }

    // C/D frag: col = lane&15, row = (lane>>4)*4 + reg
    if (z == 0) {
#pragma unroll
        for (int mi = 0; mi < 4; ++mi)
#pragma unroll
            for (int ni = 0; ni < 3; ++ni) {
                const int ml = lb + wr * 64 + mi * 16 + ((lane >> 4) << 2);
                const int ng = n0 + wc * 48 + ni * 16 + lr;
                const float bn = bias[ng];
#pragma unroll
                for (int r = 0; r < 4; ++r) {
                    const int jj = ml + r - start;
                    if (jj >= 0)
                        Eqc[((size_t)bI * kJM + jj) * kH + ng] =
                            native_exp2((acc[mi][ni][r] + bn) * kTanhScale);
                }
            }
    } else {
        __syncthreads();
        float* stg = (float*)smem;             // [128][97]
#pragma unroll
        for (int mi = 0; mi < 4; ++mi)
#pragma unroll
            for (int ni = 0; ni < 3; ++ni) {
                const int ml = wr * 64 + mi * 16 + ((lane >> 4) << 2);
                const int nl = wc * 48 + ni * 16 + lr;
                const float bn = bias[n0 + nl];
#pragma unroll
                for (int r = 0; r < 4; ++r)
                    stg[(ml + r) * 97 + nl] = native_exp2((acc[mi][ni][r] + bn) * kTanhScale);
            }
        __syncthreads();
        const int s4 = (t & 31) << 2, hb_ = t >> 5;
        const int sg = lb + s4;
#pragma unroll
        for (int u = 0; u < 12; ++u) {
            const int h = (u << 3) + hb_;
            float o[4] = { stg[(s4 + 0) * 97 + h], stg[(s4 + 1) * 97 + h],
                           stg[(s4 + 2) * 97 + h], stg[(s4 + 3) * 97 + h] };
            // sequential-h layout: Ek2[b][sg>>6][n0+h][sg&63]  (stores only where sg<start<=384)
            float* dst = Ek2 + (((size_t)bI * 6 + (sg >> 6)) * kH + n0 + h) * 64 + (sg & 63);
            if (sg + 3 < start) {
                *(float4*)dst = make_float4(o[0], o[1], o[2], o[3]);
            } else {
#pragma unroll
                for (int e2 = 0; e2 < 4; ++e2)
                    if (sg + e2 < start) dst[e2] = o[e2];
            }
        }
    }
}

// ---------------- K2: one wave per item; lane = k; 4 j-rows; 384-wide h-chunk.
// Work item derived inline from mask (scalar bucket walk; no worklist kernel).
// score~ = -2 * sum_h va[h] * rcp(Eq[b,j,h]*Ek[b,h,k] + 1)
__global__ __launch_bounds__(256) void k2_scores(
    const float* __restrict__ Eqc, const float* __restrict__ Ek2,
    const float* __restrict__ va, const int* __restrict__ mask,
    float* __restrict__ part0, float* __restrict__ part1)
{
    constexpr int JT = 4;
    const int lane = threadIdx.x & 63;
    const int wslot = (blockIdx.x << 2) | (threadIdx.x >> 6);
    const int nslots = gridDim.x << 2;

    int ne[kB];
    int ntiles = 0;
#pragma unroll
    for (int i = 0; i < kB; ++i) {
        int s = __builtin_amdgcn_readfirstlane(mask[2 * i]);
        ne[i] = ((kS - s + 3) >> 2) * ((s + 63) >> 6) * 2;
        ntiles += ne[i];
    }

    for (int w = wslot; w < ntiles; w += nslots) {
        // bucket walk: find batch b and within-batch index rem (wave-uniform scalar ops)
        int rem = w, b = 0;
#pragma unroll
        for (int i = 0; i < kB - 1; ++i) {
            bool go = (b == i) && (rem >= ne[i]);
            if (go) { rem -= ne[i]; b = i + 1; }
        }
        const int start = __builtin_amdgcn_readfirstlane(mask[2 * b]);
        const int jmax = kS - start;
        const int nkc = ((start + 63) >> 6) << 1;
        const int jt = rem / nkc;
        const int r2 = rem - jt * nkc;
        const int kt = r2 >> 1, c = r2 & 1;
        const int j0 = jt * JT, k0 = kt << 6;
        const int hbase = c * 384;

        const float* eqr[JT];
#pragma unroll
        for (int j = 0; j < JT; ++j)
            eqr[j] = Eqc + ((size_t)b * kJM + j0 + j) * kH + hbase;
        // sequential-h layout: stride 64 floats (256 B) between consecutive h
        const float* ekp = Ek2 + (((size_t)b * 6 + kt) * kH + hbase) * 64 + lane;
        const float* vap = va + hbase;

        float acc[JT] = {};
        float eA[8], eB[8];
#pragma unroll
        for (int c2 = 0; c2 < 8; ++c2) eA[c2] = ekp[(size_t)c2 * 64];
#pragma unroll
        for (int c2 = 0; c2 < 8; ++c2) eB[c2] = ekp[(size_t)(8 + c2) * 64];

        for (int h0 = 0; h0 < 384; h0 += 16) {
            const bool more = (h0 + 16) < 384;
            float nA[8], nB[8];
            if (more) {
#pragma unroll
                for (int c2 = 0; c2 < 8; ++c2) nA[c2] = ekp[(size_t)(h0 + 16 + c2) * 64];
            }
#pragma unroll
            for (int c2 = 0; c2 < 8; ++c2) {
                const float vc = vap[h0 + c2];
#pragma unroll
                for (int j = 0; j < JT; ++j) {
                    float r = __builtin_amdgcn_rcpf(fmaf(eqr[j][h0 + c2], eA[c2], 1.0f));
                    acc[j] = fmaf(vc, r, acc[j]);
                }
            }
            if (more) {
#pragma unroll
                for (int c2 = 0; c2 < 8; ++c2) nB[c2] = ekp[(size_t)(h0 + 24 + c2) * 64];
            }
#pragma unroll
            for (int c2 = 0; c2 < 8; ++c2) {
                const float vc = vap[h0 + 8 + c2];
#pragma unroll
                for (int j = 0; j < JT; ++j) {
                    float r = __builtin_amdgcn_rcpf(fmaf(eqr[j][h0 + 8 + c2], eB[c2], 1.0f));
                    acc[j] = fmaf(vc, r, acc[j]);
                }
            }
            if (more) {
#pragma unroll
                for (int c2 = 0; c2 < 8; ++c2) { eA[c2] = nA[c2]; eB[c2] = nB[c2]; }
            }
        }

        float* srow = (c ? part1 : part0) + ((size_t)b * kS + j0) * kS + k0 + lane;
#pragma unroll
        for (int j = 0; j < JT; ++j)
            if (j0 + j < jmax) srow[(size_t)j * kS] = -2.0f * acc[j];
    }
}

// ---------------- K4a: outputs[b, s<384, :] -> OT hi/lo bf16, transposed [b][h][s].
__global__ __launch_bounds__(256) void k4a_convert(
    const float* __restrict__ X,
    unsigned short* __restrict__ OThi, unsigned short* __restrict__ OTlo)
{
    __shared__ float st[64][65];
    const int b = blockIdx.z;
    const int s0 = blockIdx.y * 64;        // s0 < 384
    const int h0 = blockIdx.x * 64;
    const int t = threadIdx.x;

    const int sr = t >> 2, hc = (t & 3) << 4;
    const float* src = X + ((size_t)b * kS + s0 + sr) * kH + h0 + hc;
#pragma unroll
    for (int q = 0; q < 4; ++q) {
        float4 v = *(const float4*)(src + 4 * q);
        st[sr][hc + 4 * q + 0] = v.x;
        st[sr][hc + 4 * q + 1] = v.y;
        st[sr][hc + 4 * q + 2] = v.z;
        st[sr][hc + 4 * q + 3] = v.w;
    }
    __syncthreads();

    const int hr = t >> 2, sc = (t & 3) << 4;
    unsigned short h[16], l[16];
#pragma unroll
    for (int i = 0; i < 16; ++i) {
        float x = st[sc + i][hr];
        h[i] = bf16_rtn(x);
        float hf = __uint_as_float((unsigned)h[i] << 16);
        l[i] = bf16_rtn(x - hf);
    }
    const size_t dst = ((size_t)b * kH + h0 + hr) * kJM + s0 + sc;
    *(ushort8*)(OThi + dst)     = *(ushort8*)(h);
    *(ushort8*)(OThi + dst + 8) = *(ushort8*)(h + 8);
    *(ushort8*)(OTlo + dst)     = *(ushort8*)(l);
    *(ushort8*)(OTlo + dst + 8) = *(ushort8*)(l + 8);
}

// ---------------- K3: sum partials + row softmax over k < start; exact zeros elsewhere.
// Also emits attn bf16 hi/lo (k < 384) for the MFMA K4.
__global__ __launch_bounds__(256) void k3_softmax(
    float* __restrict__ attn, const float* __restrict__ part1,
    const int* __restrict__ mask,
    unsigned short* __restrict__ Ahi, unsigned short* __restrict__ Alo)
{
    const int bx = blockIdx.x;
    const int b = bx >> 9;
    const int j = bx & (kS - 1);
    const int start = mask[2 * b];
    float* row = attn + ((size_t)b * kS + j) * kS;
    const int tid = threadIdx.x;
    const size_t abase = ((size_t)b * kS + j) * kJM;

    if (j >= kS - start) {
        row[tid] = 0.0f;
        row[tid + 256] = 0.0f;
        Ahi[abase + tid] = 0; Alo[abase + tid] = 0;
        if (tid < 128) { Ahi[abase + 256 + tid] = 0; Alo[abase + 256 + tid] = 0; }
        return;
    }

    const float* p1row = part1 + ((size_t)b * kS + j) * kS;
    float v0 = (tid < start) ? row[tid] + p1row[tid] : -1e30f;
    float v1 = (tid + 256 < start) ? row[tid + 256] + p1row[tid + 256] : -1e30f;

    __shared__ float red[4];
    const int wid = tid >> 6;

    float m = waveMax(fmaxf(v0, v1));
    if ((tid & 63) == 0) red[wid] = m;
    __syncthreads();
    m = fmaxf(fmaxf(red[0], red[1]), fmaxf(red[2], red[3]));
    __syncthreads();

    float e0 = (tid < start) ? __expf(v0 - m) : 0.0f;
    float e1 = (tid + 256 < start) ? __expf(v1 - m) : 0.0f;
    float s = waveSum(e0 + e1);
    if ((tid & 63) == 0) red[wid] = s;
    __syncthreads();
    s = red[0] + red[1] + red[2] + red[3];

    float inv = __builtin_amdgcn_rcpf(s);
    float a0 = e0 * inv, a1 = e1 * inv;
    row[tid] = a0;
    row[tid + 256] = a1;

    unsigned short h0 = bf16_rtn(a0);
    Ahi[abase + tid] = h0;
    Alo[abase + tid] = bf16_rtn(a0 - __uint_as_float((unsigned)h0 << 16));
    if (tid < 128) {
        unsigned short h1 = bf16_rtn(a1);
        Ahi[abase + 256 + tid] = h1;
        Alo[abase + 256 + tid] = bf16_rtn(a1 - __uint_as_float((unsigned)h1 << 16));
    }
}

// ---------------- K4 (MFMA): ctx[b,j,h] = sum_k attn[b,j,k] * outputs[b,k,h]
// BM=128 (j), BN=96 (h), BK=32. 3 products: (Ahi+Alo)xBhi + AhixBlo.
__global__ __launch_bounds__(256) void k4_mfma(
    const unsigned short* __restrict__ Ahi_g, const unsigned short* __restrict__ Alo_g,
    const unsigned short* __restrict__ Bhi_g, const unsigned short* __restrict__ Blo_g,
    const int* __restrict__ mask, float* __restrict__ ctx)
{
    __shared__ char smem[35840];
    unsigned short* Ahi = (unsigned short*)smem;
    unsigned short* Alo = (unsigned short*)(smem + 10240);
    unsigned short* Bhi = (unsigned short*)(smem + 20480);
    unsigned short* Blo = (unsigned short*)(smem + 28160);

    const int m0 = blockIdx.y * 128;
    const int n0 = blockIdx.x * 96;
    const int t  = threadIdx.x;
    const int bI = m0 >> 9;
    const int jb = m0 & (kS - 1);
    const int start = mask[2 * bI];
    const int kmax = (start + 31) & ~31;

    const int ar = t >> 1, ko = (t & 1) << 4;
    const bool doB = (ar < 96);
    const size_t aoff = ((size_t)bI * kS + jb + ar) * kJM + ko;
    const size_t woff = ((size_t)bI * kH + n0 + ar) * kJM + ko;

    const int wid = t >> 6, lane = t & 63;
    const int wr = wid >> 1, wc = wid & 1;
    const int lr = lane & 15, lk = (lane >> 4) << 3;

    f32x4 acc[4][3];
#pragma unroll
    for (int mi = 0; mi < 4; ++mi)
#pragma unroll
        for (int ni = 0; ni < 3; ++ni)
#pragma unroll
            for (int r = 0; r < 4; ++r) acc[mi][ni][r] = 0.0f;

    for (int k0 = 0; k0 < kmax; k0 += 32) {
        ushort8 ah0 = *(const ushort8*)(Ahi_g + aoff + k0);
        ushort8 ah1 = *(const ushort8*)(Ahi_g + aoff + k0 + 8);
        ushort8 al0 = *(const ushort8*)(Alo_g + aoff + k0);
        ushort8 al1 = *(const ushort8*)(Alo_g + aoff + k0 + 8);
        ushort8 bh0, bh1, bl0, bl1;
        if (doB) {
            bh0 = *(const ushort8*)(Bhi_g + woff + k0);
            bh1 = *(const ushort8*)(Bhi_g + woff + k0 + 8);
            bl0 = *(const ushort8*)(Blo_g + woff + k0);
            bl1 = *(const ushort8*)(Blo_g + woff + k0 + 8);
        }
        __syncthreads();
        *(ushort8*)(Ahi + ar * 40 + ko)     = ah0;
        *(ushort8*)(Ahi + ar * 40 + ko + 8) = ah1;
        *(ushort8*)(Alo + ar * 40 + ko)     = al0;
        *(ushort8*)(Alo + ar * 40 + ko + 8) = al1;
        if (doB) {
            *(ushort8*)(Bhi + ar * 40 + ko)     = bh0;
            *(ushort8*)(Bhi + ar * 40 + ko + 8) = bh1;
            *(ushort8*)(Blo + ar * 40 + ko)     = bl0;
            *(ushort8*)(Blo + ar * 40 + ko + 8) = bl1;
        }
        __syncthreads();

        short8 ah[4], al_[4], bh[3], bl[3];
#pragma unroll
        for (int mi = 0; mi < 4; ++mi) {
            const int row = wr * 64 + mi * 16 + lr;
            ah[mi]  = *(const short8*)(Ahi + row * 40 + lk);
            al_[mi] = *(const short8*)(Alo + row * 40 + lk);
        }
#pragma unroll
        for (int ni = 0; ni < 3; ++ni) {
            const int row = wc * 48 + ni * 16 + lr;
            bh[ni] = *(const short8*)(Bhi + row * 40 + lk);
            bl[ni] = *(const short8*)(Blo + row * 40 + lk);
        }
#pragma unroll
        for (int mi = 0; mi < 4; ++mi)
#pragma unroll
            for (int ni = 0; ni < 3; ++ni)
                acc[mi][ni] = __builtin_amdgcn_mfma_f32_16x16x32_bf16(ah[mi], bh[ni], acc[mi][ni], 0, 0, 0);
#pragma unroll
        for (int mi = 0; mi < 4; ++mi)
#pragma unroll
            for (int ni = 0; ni < 3; ++ni)
                acc[mi][ni] = __builtin_amdgcn_mfma_f32_16x16x32_bf16(al_[mi], bh[ni], acc[mi][ni], 0, 0, 0);
#pragma unroll
        for (int mi = 0; mi < 4; ++mi)
#pragma unroll
            for (int ni = 0; ni < 3; ++ni)
                acc[mi][ni] = __builtin_amdgcn_mfma_f32_16x16x32_bf16(ah[mi], bl[ni], acc[mi][ni], 0, 0, 0);
    }

    // C/D frag: col = lane&15, row = (lane>>4)*4 + reg
#pragma unroll
    for (int mi = 0; mi < 4; ++mi)
#pragma unroll
        for (int ni = 0; ni < 3; ++ni) {
            const int mg = m0 + wr * 64 + mi * 16 + ((lane >> 4) << 2);
            const int ng = n0 + wc * 48 + ni * 16 + lr;
#pragma unroll
            for (int r = 0; r < 4; ++r)
                ctx[(size_t)(mg + r) * kH + ng] = acc[mi][ni][r];
        }
}

extern "C" void kernel_launch(void* const* d_in, const int* in_sizes, int n_in,
                              void* d_out, int out_size, void* d_ws, size_t ws_size,
                              hipStream_t stream)
{
    const float* outputs = (const float*)d_in[0];
    const int*   mask    = (const int*)d_in[1];
    const float* Wa_w    = (const float*)d_in[2];
    const float* Wa_b    = (const float*)d_in[3];
    const float* Ua_w    = (const float*)d_in[4];
    const float* Ua_b    = (const float*)d_in[5];
    const float* Va_w    = (const float*)d_in[6];
    // Va_b and sum(va) cancel in softmax.

    float* attn = (float*)d_out;                          // (B,S,S) 8.39 MB
    float* ctx  = attn + (size_t)kB * kS * kS;            // (B,S,H) 12.58 MB

    // Region reuse timeline (stream-ordered):
    //   ctx region:  [K0..K1] Xhi/Xlo -> [K2..K3] part1 -> [K4] contexts
    //   attn region: [K0..K1] W bf16  -> [K2..]   part0 / attentions
    //   ws Eqc:  [K1..K2] Eqc     -> [K3..K4] attn bf16 hi/lo
    //   ws Ek2:  [K1..K2] Ek2     -> [K4a..K4] OT bf16 hi/lo
    unsigned short* Xhi  = (unsigned short*)ctx;
    unsigned short* Xlo  = Xhi + (size_t)kB * kS * kH;
    unsigned short* Wahi = (unsigned short*)attn;
    unsigned short* Uahi = Wahi + (size_t)kH * kH;
    float* part1 = ctx;

    float* Eqc = (float*)((char*)d_ws + 131072);
    float* Ek2 = Eqc + (size_t)kB * kJM * kH;             // 9.44 MB each

    unsigned short* AttnHi = (unsigned short*)Eqc;
    unsigned short* AttnLo = AttnHi + (size_t)kB * kS * kJM;
    unsigned short* OThi   = (unsigned short*)Ek2;
    unsigned short* OTlo   = OThi + (size_t)kB * kH * kJM;

    // K0: RTN bf16 pre-split of X (hi/lo) and RTN bf16 of Wa/Ua
    k0_convert<<<dim3(4224), 256, 0, stream>>>(
        outputs, Wa_w, Ua_w, Xhi, Xlo, Wahi, Uahi);

    // K1 (MFMA, 2-product): Eqc (compacted rows) and Ek2 (k-block-major, sequential-h), exp applied
    k1_mfma<<<dim3(kH / 96, (kB * kS) / 128, 2), 256, 0, stream>>>(
        Xhi, Xlo, Wahi, Uahi, Wa_b, Ua_b, mask, Eqc, Ek2);

    // K2: score partials into attn (c=0) and part1 (c=1); work derived inline from mask
    k2_scores<<<dim3(2048), 256, 0, stream>>>(Eqc, Ek2, Va_w, mask, attn, part1);

    // K4a: outputs rows k<384 -> transposed bf16 hi/lo (overwrites Ek2, dead after K2)
    k4a_convert<<<dim3(kH / 64, kJM / 64, kB), 256, 0, stream>>>(outputs, OThi, OTlo);

    // K3: sum partials + softmax + exact-zero masking; emits attn bf16 hi/lo (overwrites Eqc)
    k3_softmax<<<dim3(kB * kS), 256, 0, stream>>>(attn, part1, mask, AttnHi, AttnLo);

    // K4 (MFMA, 3-product): contexts (writes every element of ctx, overwriting part1 scratch)
    k4_mfma<<<dim3(kH / 96, (kB * kS) / 128), 256, 0, stream>>>(
        AttnHi, AttnLo, OThi, OTlo, mask, ctx);
}

// Round 13
// 144.672 us; speedup vs baseline: 1.1631x; 1.1631x over previous
//
#include <hip/hip_runtime.h>

typedef float  f32x4   __attribute__((ext_vector_type(4)));
typedef short  short8  __attribute__((ext_vector_type(8)));
typedef unsigned short ushort8 __attribute__((ext_vector_type(8)));

constexpr int kB = 8;
constexpr int kS = 512;
constexpr int kH = 768;
constexpr int kJM = 384;   // max rows of Eqc / k-extent of attn-bf16 (start in [128,384))

constexpr float kTanhScale = 2.8853900817779268f;  // 2*log2(e)

__device__ __forceinline__ float native_exp2(float x) {
    float r; asm("v_exp_f32 %0, %1" : "=v"(r) : "v"(x)); return r;
}

__device__ __forceinline__ unsigned short bf16_rtn(float x) {
    unsigned u = __float_as_uint(x);
    unsigned r = u + 0x7FFFu + ((u >> 16) & 1u);   // round-to-nearest-even
    return (unsigned short)(r >> 16);
}

__device__ __forceinline__ float waveMax(float v) {
#pragma unroll
    for (int off = 32; off > 0; off >>= 1) v = fmaxf(v, __shfl_xor(v, off, 64));
    return v;
}
__device__ __forceinline__ float waveSum(float v) {
#pragma unroll
    for (int off = 32; off > 0; off >>= 1) v += __shfl_xor(v, off, 64);
    return v;
}

// ---------------- K0: X -> RTN bf16 hi + RTN lo residual; Wa/Ua -> RTN bf16 (hi only).
__global__ __launch_bounds__(256) void k0_convert(
    const float* __restrict__ X, const float* __restrict__ Wa, const float* __restrict__ Ua,
    unsigned short* __restrict__ Xhi, unsigned short* __restrict__ Xlo,
    unsigned short* __restrict__ Wahi, unsigned short* __restrict__ Uahi)
{
    const int i4 = blockIdx.x * 256 + threadIdx.x;
    if (i4 < 786432) {
        float4 v = *(const float4*)(X + (size_t)i4 * 4);
        unsigned short h[4], l[4];
#pragma unroll
        for (int c = 0; c < 4; ++c) {
            float x = (&v.x)[c];
            h[c] = bf16_rtn(x);
            float hf = __uint_as_float((unsigned)h[c] << 16);
            l[c] = bf16_rtn(x - hf);
        }
        *(ushort4*)(Xhi + (size_t)i4 * 4) = make_ushort4(h[0], h[1], h[2], h[3]);
        *(ushort4*)(Xlo + (size_t)i4 * 4) = make_ushort4(l[0], l[1], l[2], l[3]);
    } else {
        const float* src; unsigned short* hi; int off;
        if (i4 < 933888) { src = Wa; hi = Wahi; off = i4 - 786432; }
        else             { src = Ua; hi = Uahi; off = i4 - 933888; }
        float4 v = *(const float4*)(src + (size_t)off * 4);
        *(ushort4*)(hi + (size_t)off * 4) =
            make_ushort4(bf16_rtn(v.x), bf16_rtn(v.y), bf16_rtn(v.z), bf16_rtn(v.w));
    }
}

// ---------------- K1 (MFMA): z=0: Eqc[b][jj][n] = exp2((X·Wa^T+b)*s), jj = t-start
//                             z=1: Ek2[b][kt][n][s&63] = exp2((X·Ua^T+b)*s), cols s < start
// BM=128, BN=96, BK=32; 2-product bf16: (Xhi + Xlo) x W_rtn.
__global__ __launch_bounds__(256) void k1_mfma(
    const unsigned short* __restrict__ Xhi, const unsigned short* __restrict__ Xlo,
    const unsigned short* __restrict__ W0hi, const unsigned short* __restrict__ W1hi,
    const float* __restrict__ b0, const float* __restrict__ b1,
    const int* __restrict__ mask,
    float* __restrict__ Eqc, float* __restrict__ Ek2)
{
    __shared__ char smem[49664];
    unsigned short* Ahi = (unsigned short*)smem;
    unsigned short* Alo = (unsigned short*)(smem + 10240);
    unsigned short* Bhi = (unsigned short*)(smem + 20480);

    const int z = blockIdx.z;
    const unsigned short* Whi = z ? W1hi : W0hi;
    const float* bias = z ? b1 : b0;

    const int m0 = blockIdx.y * 128;
    const int n0 = blockIdx.x * 96;
    const int t  = threadIdx.x;
    const int bI = m0 >> 9;
    const int lb = m0 & (kS - 1);
    const int start = mask[2 * bI];

    if (z == 0) { if (lb + 128 <= start) return; }
    else        { if (lb >= start) return; }

    const int ar = t >> 1, ko = (t & 1) << 4;
    const bool doB = (ar < 96);
    const size_t aoff = (size_t)(m0 + ar) * kH + ko;
    const size_t woff = (size_t)(n0 + ar) * kH + ko;

    const int wid = t >> 6, lane = t & 63;
    const int wr = wid >> 1, wc = wid & 1;
    const int lr = lane & 15, lk = (lane >> 4) << 3;

    f32x4 acc[4][3];
#pragma unroll
    for (int mi = 0; mi < 4; ++mi)
#pragma unroll
        for (int ni = 0; ni < 3; ++ni)
#pragma unroll
            for (int r = 0; r < 4; ++r) acc[mi][ni][r] = 0.0f;

    for (int h0 = 0; h0 < kH; h0 += 32) {
        ushort8 ah0 = *(const ushort8*)(Xhi + aoff + h0);
        ushort8 ah1 = *(const ushort8*)(Xhi + aoff + h0 + 8);
        ushort8 al0 = *(const ushort8*)(Xlo + aoff + h0);
        ushort8 al1 = *(const ushort8*)(Xlo + aoff + h0 + 8);
        ushort8 bh0, bh1;
        if (doB) {
            bh0 = *(const ushort8*)(Whi + woff + h0);
            bh1 = *(const ushort8*)(Whi + woff + h0 + 8);
        }
        __syncthreads();
        *(ushort8*)(Ahi + ar * 40 + ko)     = ah0;
        *(ushort8*)(Ahi + ar * 40 + ko + 8) = ah1;
        *(ushort8*)(Alo + ar * 40 + ko)     = al0;
        *(ushort8*)(Alo + ar * 40 + ko + 8) = al1;
        if (doB) {
            *(ushort8*)(Bhi + ar * 40 + ko)     = bh0;
            *(ushort8*)(Bhi + ar * 40 + ko + 8) = bh1;
        }
        __syncthreads();

        short8 ah[4], al_[4], bh[3];
#pragma unroll
        for (int mi = 0; mi < 4; ++mi) {
            const int row = wr * 64 + mi * 16 + lr;
            ah[mi]  = *(const short8*)(Ahi + row * 40 + lk);
            al_[mi] = *(const short8*)(Alo + row * 40 + lk);
        }
#pragma unroll
        for (int ni = 0; ni < 3; ++ni) {
            const int row = wc * 48 + ni * 16 + lr;
            bh[ni] = *(const short8*)(Bhi + row * 40 + lk);
        }
#pragma unroll
        for (int mi = 0; mi < 4; ++mi)
#pragma unroll
            for (int ni = 0; ni < 3; ++ni)
                acc[mi][ni] = __builtin_amdgcn_mfma_f32_16x16x32_bf16(ah[mi], bh[ni], acc[mi][ni], 0, 0, 0);
#pragma unroll
        for (int mi = 0; mi < 4; ++mi)
#pragma unroll
            for (int ni = 0; ni < 3; ++ni)
                acc[mi][ni] = __builtin_amdgcn_mfma_f32_16x16x32_bf16(al_[mi], bh[ni], acc[mi][ni], 0, 0, 0);
    }

    // C/D frag: col = lane&15, row = (lane>>4)*4 + reg
    if (z == 0) {
#pragma unroll
        for (int mi = 0; mi < 4; ++mi)
#pragma unroll
            for (int ni = 0; ni < 3; ++ni) {
                const int ml = lb + wr * 64 + mi * 16 + ((lane >> 4) << 2);
                const int ng = n0 + wc * 48 + ni * 16 + lr;
                const float bn = bias[ng];
#pragma unroll
                for (int r = 0; r < 4; ++r) {
                    const int jj = ml + r - start;
                    if (jj >= 0)
                        Eqc[((size_t)bI * kJM + jj) * kH + ng] =
                            native_exp2((acc[mi][ni][r] + bn) * kTanhScale);
                }
            }
    } else {
        __syncthreads();
        float* stg = (float*)smem;             // [128][97]
#pragma unroll
        for (int mi = 0; mi < 4; ++mi)
#pragma unroll
            for (int ni = 0; ni < 3; ++ni) {
                const int ml = wr * 64 + mi * 16 + ((lane >> 4) << 2);
                const int nl = wc * 48 + ni * 16 + lr;
                const float bn = bias[n0 + nl];
#pragma unroll
                for (int r = 0; r < 4; ++r)
                    stg[(ml + r) * 97 + nl] = native_exp2((acc[mi][ni][r] + bn) * kTanhScale);
            }
        __syncthreads();
        const int s4 = (t & 31) << 2, hb_ = t >> 5;
        const int sg = lb + s4;
#pragma unroll
        for (int u = 0; u < 12; ++u) {
            const int h = (u << 3) + hb_;
            float o[4] = { stg[(s4 + 0) * 97 + h], stg[(s4 + 1) * 97 + h],
                           stg[(s4 + 2) * 97 + h], stg[(s4 + 3) * 97 + h] };
            // sequential-h layout: Ek2[b][sg>>6][n0+h][sg&63]
            float* dst = Ek2 + (((size_t)bI * 6 + (sg >> 6)) * kH + n0 + h) * 64 + (sg & 63);
            if (sg + 3 < start) {
                *(float4*)dst = make_float4(o[0], o[1], o[2], o[3]);
            } else {
#pragma unroll
                for (int e2 = 0; e2 < 4; ++e2)
                    if (sg + e2 < start) dst[e2] = o[e2];
            }
        }
    }
}

// ---------------- K2a: work list of (b, j-tile[4], k-wave[64], h-chunk[2]) items.
__global__ void k2a_worklist(const int* __restrict__ mask, int* __restrict__ wl)
{
    __shared__ int ne[kB], off[kB];
    const int tid = threadIdx.x;
    if (tid < kB) {
        int start = mask[2 * tid];
        ne[tid] = ((kS - start + 3) >> 2) * ((start + 63) >> 6) * 2;
    }
    __syncthreads();
    if (tid == 0) {
        int s = 0;
        for (int b = 0; b < kB; ++b) { off[b] = s; s += ne[b]; }
        wl[0] = s;
    }
    __syncthreads();
    for (int b = 0; b < kB; ++b) {
        int start = mask[2 * b];
        int nkw = (start + 63) >> 6;
        int nkc = nkw * 2;
        int n = ne[b], base = off[b];
        for (int t = tid; t < n; t += blockDim.x) {
            int jt = t / nkc;
            int r = t - jt * nkc;
            int kt = r >> 1, c = r & 1;
            wl[1 + base + t] = (b << 16) | (jt << 8) | (kt << 1) | c;
        }
    }
}

// ---------------- K2: one wave per item; lane = k; 4 j-rows; 384-wide h-chunk.
// score~ = -2 * sum_h va[h] * rcp(Eq[b,j,h]*Ek[b,h,k] + 1)
__global__ __launch_bounds__(256) void k2_scores(
    const float* __restrict__ Eqc, const float* __restrict__ Ek2,
    const float* __restrict__ va, const int* __restrict__ mask,
    const int* __restrict__ wl, float* __restrict__ part0, float* __restrict__ part1)
{
    constexpr int JT = 4;
    const int ntiles = wl[0];
    const int lane = threadIdx.x & 63;
    const int wslot = (blockIdx.x << 2) | (threadIdx.x >> 6);
    const int nslots = gridDim.x << 2;

    for (int w = wslot; w < ntiles; w += nslots) {
        const int e = __builtin_amdgcn_readfirstlane(wl[1 + w]);
        const int b = e >> 16, jt = (e >> 8) & 255, ktc = e & 255;
        const int kt = ktc >> 1, c = ktc & 1;
        const int start = __builtin_amdgcn_readfirstlane(mask[2 * b]);
        const int jmax = kS - start;
        const int j0 = jt * JT, k0 = kt << 6;
        const int hbase = c * 384;

        const float* eqr[JT];
#pragma unroll
        for (int j = 0; j < JT; ++j)
            eqr[j] = Eqc + ((size_t)b * kJM + j0 + j) * kH + hbase;
        // sequential-h layout: stride 64 floats (256 B) between consecutive h
        const float* ekp = Ek2 + (((size_t)b * 6 + kt) * kH + hbase) * 64 + lane;
        const float* vap = va + hbase;

        float acc[JT] = {};
        float eA[8], eB[8];
#pragma unroll
        for (int c2 = 0; c2 < 8; ++c2) eA[c2] = ekp[(size_t)c2 * 64];
#pragma unroll
        for (int c2 = 0; c2 < 8; ++c2) eB[c2] = ekp[(size_t)(8 + c2) * 64];

        for (int h0 = 0; h0 < 384; h0 += 16) {
            const bool more = (h0 + 16) < 384;
            float nA[8], nB[8];
            if (more) {
#pragma unroll
                for (int c2 = 0; c2 < 8; ++c2) nA[c2] = ekp[(size_t)(h0 + 16 + c2) * 64];
            }
#pragma unroll
            for (int c2 = 0; c2 < 8; ++c2) {
                const float vc = vap[h0 + c2];
#pragma unroll
                for (int j = 0; j < JT; ++j) {
                    float r = __builtin_amdgcn_rcpf(fmaf(eqr[j][h0 + c2], eA[c2], 1.0f));
                    acc[j] = fmaf(vc, r, acc[j]);
                }
            }
            if (more) {
#pragma unroll
                for (int c2 = 0; c2 < 8; ++c2) nB[c2] = ekp[(size_t)(h0 + 24 + c2) * 64];
            }
#pragma unroll
            for (int c2 = 0; c2 < 8; ++c2) {
                const float vc = vap[h0 + 8 + c2];
#pragma unroll
                for (int j = 0; j < JT; ++j) {
                    float r = __builtin_amdgcn_rcpf(fmaf(eqr[j][h0 + 8 + c2], eB[c2], 1.0f));
                    acc[j] = fmaf(vc, r, acc[j]);
                }
            }
            if (more) {
#pragma unroll
                for (int c2 = 0; c2 < 8; ++c2) { eA[c2] = nA[c2]; eB[c2] = nB[c2]; }
            }
        }

        float* srow = (c ? part1 : part0) + ((size_t)b * kS + j0) * kS + k0 + lane;
#pragma unroll
        for (int j = 0; j < JT; ++j)
            if (j0 + j < jmax) srow[(size_t)j * kS] = -2.0f * acc[j];
    }
}

// ---------------- K4a: outputs[b, s<384, :] -> OT hi/lo bf16, transposed [b][h][s].
__global__ __launch_bounds__(256) void k4a_convert(
    const float* __restrict__ X,
    unsigned short* __restrict__ OThi, unsigned short* __restrict__ OTlo)
{
    __shared__ float st[64][65];
    const int b = blockIdx.z;
    const int s0 = blockIdx.y * 64;        // s0 < 384
    const int h0 = blockIdx.x * 64;
    const int t = threadIdx.x;

    const int sr = t >> 2, hc = (t & 3) << 4;
    const float* src = X + ((size_t)b * kS + s0 + sr) * kH + h0 + hc;
#pragma unroll
    for (int q = 0; q < 4; ++q) {
        float4 v = *(const float4*)(src + 4 * q);
        st[sr][hc + 4 * q + 0] = v.x;
        st[sr][hc + 4 * q + 1] = v.y;
        st[sr][hc + 4 * q + 2] = v.z;
        st[sr][hc + 4 * q + 3] = v.w;
    }
    __syncthreads();

    const int hr = t >> 2, sc = (t & 3) << 4;
    unsigned short h[16], l[16];
#pragma unroll
    for (int i = 0; i < 16; ++i) {
        float x = st[sc + i][hr];
        h[i] = bf16_rtn(x);
        float hf = __uint_as_float((unsigned)h[i] << 16);
        l[i] = bf16_rtn(x - hf);
    }
    const size_t dst = ((size_t)b * kH + h0 + hr) * kJM + s0 + sc;
    *(ushort8*)(OThi + dst)     = *(ushort8*)(h);
    *(ushort8*)(OThi + dst + 8) = *(ushort8*)(h + 8);
    *(ushort8*)(OTlo + dst)     = *(ushort8*)(l);
    *(ushort8*)(OTlo + dst + 8) = *(ushort8*)(l + 8);
}

// ---------------- K3: sum partials + row softmax over k < start; exact zeros elsewhere.
// Also emits attn bf16 hi/lo (k < 384) for the MFMA K4.
__global__ __launch_bounds__(256) void k3_softmax(
    float* __restrict__ attn, const float* __restrict__ part1,
    const int* __restrict__ mask,
    unsigned short* __restrict__ Ahi, unsigned short* __restrict__ Alo)
{
    const int bx = blockIdx.x;
    const int b = bx >> 9;
    const int j = bx & (kS - 1);
    const int start = mask[2 * b];
    float* row = attn + ((size_t)b * kS + j) * kS;
    const int tid = threadIdx.x;
    const size_t abase = ((size_t)b * kS + j) * kJM;

    if (j >= kS - start) {
        row[tid] = 0.0f;
        row[tid + 256] = 0.0f;
        Ahi[abase + tid] = 0; Alo[abase + tid] = 0;
        if (tid < 128) { Ahi[abase + 256 + tid] = 0; Alo[abase + 256 + tid] = 0; }
        return;
    }

    const float* p1row = part1 + ((size_t)b * kS + j) * kS;
    float v0 = (tid < start) ? row[tid] + p1row[tid] : -1e30f;
    float v1 = (tid + 256 < start) ? row[tid + 256] + p1row[tid + 256] : -1e30f;

    __shared__ float red[4];
    const int wid = tid >> 6;

    float m = waveMax(fmaxf(v0, v1));
    if ((tid & 63) == 0) red[wid] = m;
    __syncthreads();
    m = fmaxf(fmaxf(red[0], red[1]), fmaxf(red[2], red[3]));
    __syncthreads();

    float e0 = (tid < start) ? __expf(v0 - m) : 0.0f;
    float e1 = (tid + 256 < start) ? __expf(v1 - m) : 0.0f;
    float s = waveSum(e0 + e1);
    if ((tid & 63) == 0) red[wid] = s;
    __syncthreads();
    s = red[0] + red[1] + red[2] + red[3];

    float inv = __builtin_amdgcn_rcpf(s);
    float a0 = e0 * inv, a1 = e1 * inv;
    row[tid] = a0;
    row[tid + 256] = a1;

    unsigned short h0 = bf16_rtn(a0);
    Ahi[abase + tid] = h0;
    Alo[abase + tid] = bf16_rtn(a0 - __uint_as_float((unsigned)h0 << 16));
    if (tid < 128) {
        unsigned short h1 = bf16_rtn(a1);
        Ahi[abase + 256 + tid] = h1;
        Alo[abase + 256 + tid] = bf16_rtn(a1 - __uint_as_float((unsigned)h1 << 16));
    }
}

// ---------------- K4 (MFMA): ctx[b,j,h] = sum_k attn[b,j,k] * outputs[b,k,h]
// BM=128 (j), BN=96 (h), BK=32. 3 products: (Ahi+Alo)xBhi + AhixBlo.
__global__ __launch_bounds__(256) void k4_mfma(
    const unsigned short* __restrict__ Ahi_g, const unsigned short* __restrict__ Alo_g,
    const unsigned short* __restrict__ Bhi_g, const unsigned short* __restrict__ Blo_g,
    const int* __restrict__ mask, float* __restrict__ ctx)
{
    __shared__ char smem[35840];
    unsigned short* Ahi = (unsigned short*)smem;
    unsigned short* Alo = (unsigned short*)(smem + 10240);
    unsigned short* Bhi = (unsigned short*)(smem + 20480);
    unsigned short* Blo = (unsigned short*)(smem + 28160);

    const int m0 = blockIdx.y * 128;
    const int n0 = blockIdx.x * 96;
    const int t  = threadIdx.x;
    const int bI = m0 >> 9;
    const int jb = m0 & (kS - 1);
    const int start = mask[2 * bI];
    const int kmax = (start + 31) & ~31;

    const int ar = t >> 1, ko = (t & 1) << 4;
    const bool doB = (ar < 96);
    const size_t aoff = ((size_t)bI * kS + jb + ar) * kJM + ko;
    const size_t woff = ((size_t)bI * kH + n0 + ar) * kJM + ko;

    const int wid = t >> 6, lane = t & 63;
    const int wr = wid >> 1, wc = wid & 1;
    const int lr = lane & 15, lk = (lane >> 4) << 3;

    f32x4 acc[4][3];
#pragma unroll
    for (int mi = 0; mi < 4; ++mi)
#pragma unroll
        for (int ni = 0; ni < 3; ++ni)
#pragma unroll
            for (int r = 0; r < 4; ++r) acc[mi][ni][r] = 0.0f;

    for (int k0 = 0; k0 < kmax; k0 += 32) {
        ushort8 ah0 = *(const ushort8*)(Ahi_g + aoff + k0);
        ushort8 ah1 = *(const ushort8*)(Ahi_g + aoff + k0 + 8);
        ushort8 al0 = *(const ushort8*)(Alo_g + aoff + k0);
        ushort8 al1 = *(const ushort8*)(Alo_g + aoff + k0 + 8);
        ushort8 bh0, bh1, bl0, bl1;
        if (doB) {
            bh0 = *(const ushort8*)(Bhi_g + woff + k0);
            bh1 = *(const ushort8*)(Bhi_g + woff + k0 + 8);
            bl0 = *(const ushort8*)(Blo_g + woff + k0);
            bl1 = *(const ushort8*)(Blo_g + woff + k0 + 8);
        }
        __syncthreads();
        *(ushort8*)(Ahi + ar * 40 + ko)     = ah0;
        *(ushort8*)(Ahi + ar * 40 + ko + 8) = ah1;
        *(ushort8*)(Alo + ar * 40 + ko)     = al0;
        *(ushort8*)(Alo + ar * 40 + ko + 8) = al1;
        if (doB) {
            *(ushort8*)(Bhi + ar * 40 + ko)     = bh0;
            *(ushort8*)(Bhi + ar * 40 + ko + 8) = bh1;
            *(ushort8*)(Blo + ar * 40 + ko)     = bl0;
            *(ushort8*)(Blo + ar * 40 + ko + 8) = bl1;
        }
        __syncthreads();

        short8 ah[4], al_[4], bh[3], bl[3];
#pragma unroll
        for (int mi = 0; mi < 4; ++mi) {
            const int row = wr * 64 + mi * 16 + lr;
            ah[mi]  = *(const short8*)(Ahi + row * 40 + lk);
            al_[mi] = *(const short8*)(Alo + row * 40 + lk);
        }
#pragma unroll
        for (int ni = 0; ni < 3; ++ni) {
            const int row = wc * 48 + ni * 16 + lr;
            bh[ni] = *(const short8*)(Bhi + row * 40 + lk);
            bl[ni] = *(const short8*)(Blo + row * 40 + lk);
        }
#pragma unroll
        for (int mi = 0; mi < 4; ++mi)
#pragma unroll
            for (int ni = 0; ni < 3; ++ni)
                acc[mi][ni] = __builtin_amdgcn_mfma_f32_16x16x32_bf16(ah[mi], bh[ni], acc[mi][ni], 0, 0, 0);
#pragma unroll
        for (int mi = 0; mi < 4; ++mi)
#pragma unroll
            for (int ni = 0; ni < 3; ++ni)
                acc[mi][ni] = __builtin_amdgcn_mfma_f32_16x16x32_bf16(al_[mi], bh[ni], acc[mi][ni], 0, 0, 0);
#pragma unroll
        for (int mi = 0; mi < 4; ++mi)
#pragma unroll
            for (int ni = 0; ni < 3; ++ni)
                acc[mi][ni] = __builtin_amdgcn_mfma_f32_16x16x32_bf16(ah[mi], bl[ni], acc[mi][ni], 0, 0, 0);
    }

    // C/D frag: col = lane&15, row = (lane>>4)*4 + reg
#pragma unroll
    for (int mi = 0; mi < 4; ++mi)
#pragma unroll
        for (int ni = 0; ni < 3; ++ni) {
            const int mg = m0 + wr * 64 + mi * 16 + ((lane >> 4) << 2);
            const int ng = n0 + wc * 48 + ni * 16 + lr;
#pragma unroll
            for (int r = 0; r < 4; ++r)
                ctx[(size_t)(mg + r) * kH + ng] = acc[mi][ni][r];
        }
}

extern "C" void kernel_launch(void* const* d_in, const int* in_sizes, int n_in,
                              void* d_out, int out_size, void* d_ws, size_t ws_size,
                              hipStream_t stream)
{
    const float* outputs = (const float*)d_in[0];
    const int*   mask    = (const int*)d_in[1];
    const float* Wa_w    = (const float*)d_in[2];
    const float* Wa_b    = (const float*)d_in[3];
    const float* Ua_w    = (const float*)d_in[4];
    const float* Ua_b    = (const float*)d_in[5];
    const float* Va_w    = (const float*)d_in[6];
    // Va_b and sum(va) cancel in softmax.

    float* attn = (float*)d_out;                          // (B,S,S) 8.39 MB
    float* ctx  = attn + (size_t)kB * kS * kS;            // (B,S,H) 12.58 MB

    // Region reuse timeline (stream-ordered):
    //   ctx region:  [K0..K1] Xhi/Xlo -> [K2..K3] part1 -> [K4] contexts
    //   attn region: [K0..K1] W bf16  -> [K2..]   part0 / attentions
    //   ws Eqc:  [K1..K2] Eqc     -> [K3..K4] attn bf16 hi/lo
    //   ws Ek2:  [K1..K2] Ek2     -> [K4a..K4] OT bf16 hi/lo
    unsigned short* Xhi  = (unsigned short*)ctx;
    unsigned short* Xlo  = Xhi + (size_t)kB * kS * kH;
    unsigned short* Wahi = (unsigned short*)attn;
    unsigned short* Uahi = Wahi + (size_t)kH * kH;
    float* part1 = ctx;

    int* wl = (int*)d_ws;
    float* Eqc = (float*)((char*)d_ws + 131072);
    float* Ek2 = Eqc + (size_t)kB * kJM * kH;             // 9.44 MB each

    unsigned short* AttnHi = (unsigned short*)Eqc;
    unsigned short* AttnLo = AttnHi + (size_t)kB * kS * kJM;
    unsigned short* OThi   = (unsigned short*)Ek2;
    unsigned short* OTlo   = OThi + (size_t)kB * kH * kJM;

    // K0: RTN bf16 pre-split of X (hi/lo) and RTN bf16 of Wa/Ua
    k0_convert<<<dim3(4224), 256, 0, stream>>>(
        outputs, Wa_w, Ua_w, Xhi, Xlo, Wahi, Uahi);

    // K1 (MFMA, 2-product): Eqc (compacted rows) and Ek2 (k-block-major, sequential-h)
    k1_mfma<<<dim3(kH / 96, (kB * kS) / 128, 2), 256, 0, stream>>>(
        Xhi, Xlo, Wahi, Uahi, Wa_b, Ua_b, mask, Eqc, Ek2);

    // K2a + K2: score partials into attn (c=0) and part1 (c=1)
    k2a_worklist<<<dim3(1), 256, 0, stream>>>(mask, wl);
    k2_scores<<<dim3(2048), 256, 0, stream>>>(Eqc, Ek2, Va_w, mask, wl, attn, part1);

    // K4a: outputs rows k<384 -> transposed bf16 hi/lo (overwrites Ek2, dead after K2)
    k4a_convert<<<dim3(kH / 64, kJM / 64, kB), 256, 0, stream>>>(outputs, OThi, OTlo);

    // K3: sum partials + softmax + exact-zero masking; emits attn bf16 hi/lo (overwrites Eqc)
    k3_softmax<<<dim3(kB * kS), 256, 0, stream>>>(attn, part1, mask, AttnHi, AttnLo);

    // K4 (MFMA, 3-product): contexts (writes every element of ctx, overwriting part1 scratch)
    k4_mfma<<<dim3(kH / 96, (kB * kS) / 128), 256, 0, stream>>>(
        AttnHi, AttnLo, OThi, OTlo, mask, ctx);
}